// Round 3
// baseline (226.088 us; speedup 1.0000x reference)
//
#include <hip/hip_runtime.h>
#include <math.h>

#define BB 2
#define SS 2048
#define DDIM 768
#define HH 12
#define DH 64
#define NROWS (BB*SS)            // 4096
#define NTOK_D (NROWS*DDIM)      // 3145728

typedef _Float16 f16;
typedef _Float16 half4 __attribute__((ext_vector_type(4)));
typedef _Float16 half8 __attribute__((ext_vector_type(8)));
typedef float f32x4 __attribute__((ext_vector_type(4)));

#define MFMA16(a,b,c) __builtin_amdgcn_mfma_f32_16x16x32_f16((a),(b),(c),0,0,0)
#define QSCALE (0.125f * 1.44269504088896f)   // head-dim scale * log2(e)

// swizzled byte offset inside a 128B LDS row: 16B slot index ^= (row&7)
__device__ __forceinline__ int swz(int row, int chunk16) {
    return row*128 + ((chunk16 ^ (row & 7)) << 4);
}

// ---------------------------------------------------------------------------
// prep: x (f32) -> Xh (f16). 1536 blocks x 256 thr, 8 elems/thread.
// ---------------------------------------------------------------------------
__global__ __launch_bounds__(256) void prep_x(const float* __restrict__ x, f16* __restrict__ xh)
{
    int i = blockIdx.x * 256 + threadIdx.x;
    const float4* in = (const float4*)x;
    float4 a = in[i*2], b = in[i*2+1];
    half8 h = {(f16)a.x,(f16)a.y,(f16)a.z,(f16)a.w,(f16)b.x,(f16)b.y,(f16)b.z,(f16)b.w};
    *(half8*)(xh + (size_t)i*8) = h;
}

// ---------------------------------------------------------------------------
// prep: W[k][n] (f32) -> Wt[n][k] (f16), 4 matrices. grid (12,12,4), 256 thr.
// ---------------------------------------------------------------------------
__global__ __launch_bounds__(256) void prep_w(const float* __restrict__ Wq, const float* __restrict__ Wk,
                                              const float* __restrict__ Wv, const float* __restrict__ Wo,
                                              f16* __restrict__ Wt)
{
    const int z = blockIdx.z;
    const float* W = z==0 ? Wq : (z==1 ? Wk : (z==2 ? Wv : Wo));
    f16* out = Wt + (size_t)z * DDIM * DDIM;

    __shared__ float tile[64][65];
    const int t = threadIdx.x;
    const int k0 = blockIdx.x*64, n0 = blockIdx.y*64;

    const int kr = t >> 2, nc = (t & 3) * 16;
    #pragma unroll
    for (int i = 0; i < 4; ++i) {
        float4 v = *(const float4*)&W[(size_t)(k0+kr)*DDIM + n0 + nc + i*4];
        tile[kr][nc+i*4+0] = v.x; tile[kr][nc+i*4+1] = v.y;
        tile[kr][nc+i*4+2] = v.z; tile[kr][nc+i*4+3] = v.w;
    }
    __syncthreads();
    const int nr = t >> 2, kc = (t & 3) * 16;
    half8 h0, h1;
    #pragma unroll
    for (int j = 0; j < 8; ++j) {
        h0[j] = (f16)tile[kc + j][nr];
        h1[j] = (f16)tile[kc + 8 + j][nr];
    }
    *(half8*)&out[(size_t)(n0+nr)*DDIM + k0 + kc]     = h0;
    *(half8*)&out[(size_t)(n0+nr)*DDIM + k0 + kc + 8] = h1;
}

// ---------------------------------------------------------------------------
// QKV projection: C = Xh @ Wz + bias. q -> [B,H,S,Dh] pre-scaled by QSCALE,
// k -> [B,H,S,Dh], v -> TRANSPOSED [B,H,Dh,S].
// grid (4096/64, 768/128, 3), 256 thr (4 waves 2x2), BK=64, 16x16x32 MFMA.
// ---------------------------------------------------------------------------
__global__ __launch_bounds__(256) void proj_qkv(const f16* __restrict__ Xh, const f16* __restrict__ Wt,
        const float* __restrict__ bq, const float* __restrict__ bk, const float* __restrict__ bv,
        f16* __restrict__ qb, f16* __restrict__ kb2, f16* __restrict__ vtb)
{
    const int z = blockIdx.z;
    const f16* Wz = Wt + (size_t)z * DDIM * DDIM;
    const float* bias = z==0 ? bq : (z==1 ? bk : bv);
    const float qscale = (z==0) ? QSCALE : 1.0f;

    __shared__ __align__(16) unsigned char lds[24*1024];
    unsigned char* As = lds;            // 64 rows x 128B (m x k f16)
    unsigned char* Bs = lds + 8*1024;   // 128 rows x 128B (n x k f16)

    const int tid = threadIdx.x;
    const int l = tid & 63, w = tid >> 6;
    const int wm = w >> 1, wn = w & 1;
    const int m0 = blockIdx.x * 64, n0 = blockIdx.y * 128;

    f32x4 acc[2][4];
    #pragma unroll
    for (int i=0;i<2;i++)
        #pragma unroll
        for (int j=0;j<4;j++) { f32x4 zv = {0.f,0.f,0.f,0.f}; acc[i][j] = zv; }

    for (int k0 = 0; k0 < DDIM; k0 += 64) {
        __syncthreads();
        #pragma unroll
        for (int i = 0; i < 2; ++i) {
            int c = tid + i*256;
            int row = c >> 3, kc = c & 7;
            half8 v = *(const half8*)&Xh[(size_t)(m0+row)*DDIM + k0 + kc*8];
            *(half8*)(As + swz(row, kc)) = v;
        }
        #pragma unroll
        for (int i = 0; i < 4; ++i) {
            int c = tid + i*256;
            int row = c >> 3, kc = c & 7;
            half8 v = *(const half8*)&Wz[(size_t)(n0+row)*DDIM + k0 + kc*8];
            *(half8*)(Bs + swz(row, kc)) = v;
        }
        __syncthreads();

        half8 af[2][2], bf[4][2];
        #pragma unroll
        for (int mt = 0; mt < 2; ++mt) {
            int row = wm*32 + mt*16 + (l & 15);
            #pragma unroll
            for (int kh = 0; kh < 2; ++kh)
                af[mt][kh] = *(const half8*)(As + swz(row, kh*4 + (l>>4)));
        }
        #pragma unroll
        for (int nt = 0; nt < 4; ++nt) {
            int row = wn*64 + nt*16 + (l & 15);
            #pragma unroll
            for (int kh = 0; kh < 2; ++kh)
                bf[nt][kh] = *(const half8*)(Bs + swz(row, kh*4 + (l>>4)));
        }
        #pragma unroll
        for (int mt = 0; mt < 2; ++mt)
            #pragma unroll
            for (int nt = 0; nt < 4; ++nt) {
                acc[mt][nt] = MFMA16(af[mt][0], bf[nt][0], acc[mt][nt]);
                acc[mt][nt] = MFMA16(af[mt][1], bf[nt][1], acc[mt][nt]);
            }
    }

    if (z == 2) {
        // V transposed: [B,H,Dh,S]; r-quad is contiguous in s -> half4 store
        #pragma unroll
        for (int mt = 0; mt < 2; ++mt)
            #pragma unroll
            for (int nt = 0; nt < 4; ++nt) {
                int m = m0 + wm*32 + mt*16 + (l>>4)*4;   // s base (r=0)
                int n = n0 + wn*64 + nt*16 + (l & 15);
                int b = m >> 11, s = m & 2047;
                int h = n >> 6,  d = n & 63;
                float bs = bias[n];
                half4 o4 = {(f16)(acc[mt][nt][0] + bs), (f16)(acc[mt][nt][1] + bs),
                            (f16)(acc[mt][nt][2] + bs), (f16)(acc[mt][nt][3] + bs)};
                *(half4*)&vtb[(((size_t)(b*HH + h))*DH + d)*SS + s] = o4;
            }
    } else {
        f16* out = (z == 0) ? qb : kb2;
        #pragma unroll
        for (int mt = 0; mt < 2; ++mt)
            #pragma unroll
            for (int nt = 0; nt < 4; ++nt)
                #pragma unroll
                for (int r = 0; r < 4; ++r) {
                    int m = m0 + wm*32 + mt*16 + (l>>4)*4 + r;
                    int n = n0 + wn*64 + nt*16 + (l & 15);
                    float v = (acc[mt][nt][r] + bias[n]) * qscale;
                    int b = m >> 11, s = m & 2047;
                    int h = n >> 6,  d = n & 63;
                    out[(((size_t)(b*HH + h))*SS + s)*DH + d] = (f16)v;
                }
    }
}

// ---------------------------------------------------------------------------
// Flash attention, swapped-operand MFMA, no K/V LDS staging, no barriers.
// grid (32, 12, 2), 256 thr = 4 independent waves x 16 q-rows each.
// QK^T: mfma(K, Q) -> S[key][q]; PV: mfma(V^T, P) -> O[d][q].
// P goes through a 2KB per-wave swizzled LDS buffer to re-layout.
// ---------------------------------------------------------------------------
__global__ __launch_bounds__(256, 3) void attn_mfma(
        const f16* __restrict__ qbuf, const f16* __restrict__ kbuf,
        const f16* __restrict__ vtbuf, f16* __restrict__ obuf)
{
    __shared__ __align__(16) unsigned char Ps[8192];   // 4 waves x 2KB

    const int tid = threadIdx.x;
    const int l = tid & 63, w = tid >> 6;
    const int g = l >> 4, qi = l & 15;
    const int q0w = blockIdx.x * 64 + w * 16;
    const size_t base   = ((size_t)(blockIdx.z * HH + blockIdx.y)) * SS * DH;  // q,k,o
    const size_t vtbase = base;                                                 // v^T same extent
    unsigned char* Pw = Ps + w * 2048;

    // Q B-frags: lane n=q=qi, k=d = kh*32 + g*8 + j   (q pre-scaled)
    half8 qf[2];
    #pragma unroll
    for (int kh = 0; kh < 2; ++kh)
        qf[kh] = *(const half8*)&qbuf[base + (size_t)(q0w + qi)*DH + kh*32 + g*8];

    f32x4 oacc[4];
    #pragma unroll
    for (int i = 0; i < 4; ++i) { f32x4 zv = {0.f,0.f,0.f,0.f}; oacc[i] = zv; }
    float mrun = -INFINITY;
    float lsum = 0.f;

    half8 ka[8], kb[8], va[8];

    // K A-frag loads for tile t: lane m=key=mt*16+qi, k=d=kh*32+g*8+j
#define LOADK(arr, t) { \
        const f16* kp = kbuf + base + (size_t)(t) * 64 * DH; \
        _Pragma("unroll") \
        for (int mt = 0; mt < 4; ++mt) \
            _Pragma("unroll") \
            for (int kh = 0; kh < 2; ++kh) \
                arr[mt*2+kh] = *(const half8*)&kp[(mt*16 + qi)*DH + kh*32 + g*8]; }

    // V^T A-frag loads: lane m=d=dt*16+qi, k=key=kh*32+g*8+j
#define LOADV(arr, t) { \
        const f16* vp = vtbuf + vtbase + (t) * 64; \
        _Pragma("unroll") \
        for (int dt = 0; dt < 4; ++dt) \
            _Pragma("unroll") \
            for (int kh = 0; kh < 2; ++kh) \
                arr[dt*2+kh] = *(const half8*)&vp[(size_t)(dt*16 + qi)*SS + kh*32 + g*8]; }

#define TILE_BODY(KCUR, KNXT, t) { \
        LOADV(va, t); \
        f32x4 sv[4]; \
        _Pragma("unroll") \
        for (int mt = 0; mt < 4; ++mt) { \
            f32x4 zz = {0.f,0.f,0.f,0.f}; \
            zz = MFMA16(KCUR[mt*2+0], qf[0], zz); \
            sv[mt] = MFMA16(KCUR[mt*2+1], qf[1], zz); \
        } \
        int tn = (t) + 1 < 32 ? (t) + 1 : 31; \
        LOADK(KNXT, tn); \
        /* softmax: lane owns q=q0w+qi, keys t*64 + mt*16 + g*4 + r */ \
        float lm = -INFINITY; \
        _Pragma("unroll") \
        for (int mt = 0; mt < 4; ++mt) \
            _Pragma("unroll") \
            for (int r = 0; r < 4; ++r) lm = fmaxf(lm, sv[mt][r]); \
        lm = fmaxf(lm, __shfl_xor(lm, 16)); \
        lm = fmaxf(lm, __shfl_xor(lm, 32)); \
        float mnew = fmaxf(mrun, lm); \
        float fsc = exp2f(mrun - mnew); \
        mrun = mnew; \
        float rs = 0.f; \
        _Pragma("unroll") \
        for (int mt = 0; mt < 4; ++mt) \
            _Pragma("unroll") \
            for (int r = 0; r < 4; ++r) { \
                float pv = exp2f(sv[mt][r] - mnew); \
                sv[mt][r] = pv; rs += pv; \
            } \
        rs += __shfl_xor(rs, 16); \
        rs += __shfl_xor(rs, 32); \
        lsum = lsum * fsc + rs; \
        _Pragma("unroll") \
        for (int dt = 0; dt < 4; ++dt) \
            _Pragma("unroll") \
            for (int r = 0; r < 4; ++r) oacc[dt][r] *= fsc; \
        /* P -> per-wave LDS: row q=qi, key col = mt*32+g*8 bytes, half4 */ \
        _Pragma("unroll") \
        for (int mt = 0; mt < 4; ++mt) { \
            half4 pk = {(f16)sv[mt][0], (f16)sv[mt][1], (f16)sv[mt][2], (f16)sv[mt][3]}; \
            *(half4*)(Pw + swz(qi, 2*mt + (g>>1)) + (g&1)*8) = pk; \
        } \
        /* P B-frags: lane n=q=qi, k=key = kh*32 + g*8 + j */ \
        half8 pf0 = *(const half8*)(Pw + swz(qi, 0*4 + g)); \
        half8 pf1 = *(const half8*)(Pw + swz(qi, 1*4 + g)); \
        _Pragma("unroll") \
        for (int dt = 0; dt < 4; ++dt) { \
            oacc[dt] = MFMA16(va[dt*2+0], pf0, oacc[dt]); \
            oacc[dt] = MFMA16(va[dt*2+1], pf1, oacc[dt]); \
        } }

    LOADK(ka, 0);
    for (int t = 0; t < 32; t += 2) {
        TILE_BODY(ka, kb, t);
        TILE_BODY(kb, ka, t + 1);
    }

    // epilogue: O[d][q] -> obuf[B,H,S,Dh]; lsum is lane-local (q=qi)
    const float inv = 1.0f / lsum;
    #pragma unroll
    for (int dt = 0; dt < 4; ++dt) {
        half4 o4 = {(f16)(oacc[dt][0]*inv), (f16)(oacc[dt][1]*inv),
                    (f16)(oacc[dt][2]*inv), (f16)(oacc[dt][3]*inv)};
        *(half4*)&obuf[base + (size_t)(q0w + qi)*DH + dt*16 + g*4] = o4;
    }
#undef TILE_BODY
#undef LOADK
#undef LOADV
}

// ---------------------------------------------------------------------------
// Output projection: C = obuf(gathered) @ Wo' + bo -> f32 out [4096][768].
// grid (64, 6), 256 thr.
// ---------------------------------------------------------------------------
__global__ __launch_bounds__(256) void proj_out(const f16* __restrict__ obuf, const f16* __restrict__ Wt,
                                                const float* __restrict__ bo, float* __restrict__ out)
{
    const f16* Wz = Wt + (size_t)3 * DDIM * DDIM;

    __shared__ __align__(16) unsigned char lds[24*1024];
    unsigned char* As = lds;
    unsigned char* Bs = lds + 8*1024;

    const int tid = threadIdx.x;
    const int l = tid & 63, w = tid >> 6;
    const int wm = w >> 1, wn = w & 1;
    const int m0 = blockIdx.x * 64, n0 = blockIdx.y * 128;

    f32x4 acc[2][4];
    #pragma unroll
    for (int i=0;i<2;i++)
        #pragma unroll
        for (int j=0;j<4;j++) { f32x4 zv = {0.f,0.f,0.f,0.f}; acc[i][j] = zv; }

    for (int k0 = 0; k0 < DDIM; k0 += 64) {
        const int h = k0 >> 6;
        __syncthreads();
        #pragma unroll
        for (int i = 0; i < 2; ++i) {
            int c = tid + i*256;
            int row = c >> 3, kc = c & 7;
            int m = m0 + row, b = m >> 11, s = m & 2047;
            half8 v = *(const half8*)&obuf[(((size_t)(b*HH + h))*SS + s)*DH + kc*8];
            *(half8*)(As + swz(row, kc)) = v;
        }
        #pragma unroll
        for (int i = 0; i < 4; ++i) {
            int c = tid + i*256;
            int row = c >> 3, kc = c & 7;
            half8 v = *(const half8*)&Wz[(size_t)(n0+row)*DDIM + k0 + kc*8];
            *(half8*)(Bs + swz(row, kc)) = v;
        }
        __syncthreads();

        half8 af[2][2], bf[4][2];
        #pragma unroll
        for (int mt = 0; mt < 2; ++mt) {
            int row = wm*32 + mt*16 + (l & 15);
            #pragma unroll
            for (int kh = 0; kh < 2; ++kh)
                af[mt][kh] = *(const half8*)(As + swz(row, kh*4 + (l>>4)));
        }
        #pragma unroll
        for (int nt = 0; nt < 4; ++nt) {
            int row = wn*64 + nt*16 + (l & 15);
            #pragma unroll
            for (int kh = 0; kh < 2; ++kh)
                bf[nt][kh] = *(const half8*)(Bs + swz(row, kh*4 + (l>>4)));
        }
        #pragma unroll
        for (int mt = 0; mt < 2; ++mt)
            #pragma unroll
            for (int nt = 0; nt < 4; ++nt) {
                acc[mt][nt] = MFMA16(af[mt][0], bf[nt][0], acc[mt][nt]);
                acc[mt][nt] = MFMA16(af[mt][1], bf[nt][1], acc[mt][nt]);
            }
    }

    #pragma unroll
    for (int mt = 0; mt < 2; ++mt)
        #pragma unroll
        for (int nt = 0; nt < 4; ++nt)
            #pragma unroll
            for (int r = 0; r < 4; ++r) {
                int m = m0 + wm*32 + mt*16 + (l>>4)*4 + r;
                int n = n0 + wn*64 + nt*16 + (l & 15);
                out[(size_t)m*DDIM + n] = acc[mt][nt][r] + bo[n];
            }
}

// ---------------------------------------------------------------------------
extern "C" void kernel_launch(void* const* d_in, const int* in_sizes, int n_in,
                              void* d_out, int out_size, void* d_ws, size_t ws_size,
                              hipStream_t stream)
{
    const float* x  = (const float*)d_in[0];
    const float* Wq = (const float*)d_in[1];
    const float* bq = (const float*)d_in[2];
    const float* Wk = (const float*)d_in[3];
    const float* bk = (const float*)d_in[4];
    const float* Wv = (const float*)d_in[5];
    const float* bv = (const float*)d_in[6];
    const float* Wo = (const float*)d_in[7];
    const float* bo = (const float*)d_in[8];

    char* ws = (char*)d_ws;
    const size_t XH_B  = (size_t)NTOK_D * 2;            // 6,291,456
    const size_t WT_B  = (size_t)4 * DDIM * DDIM * 2;   // 4,718,592
    const size_t HB_B  = (size_t)BB * HH * SS * DH * 2; // 6,291,456

    f16* Xh = (f16*)ws;
    f16* Wt = (f16*)(ws + XH_B);
    f16* qb = (f16*)(ws + XH_B + WT_B);
    f16* kb = (f16*)(ws + XH_B + WT_B + HB_B);
    f16* vt = (f16*)(ws + XH_B + WT_B + 2*HB_B);        // [B,H,Dh,S]
    f16* ob = (f16*)(ws + XH_B + WT_B + 3*HB_B);        // end ~36.2 MB

    prep_x<<<NTOK_D/(256*8), 256, 0, stream>>>(x, Xh);
    prep_w<<<dim3(DDIM/64, DDIM/64, 4), 256, 0, stream>>>(Wq, Wk, Wv, Wo, Wt);
    proj_qkv<<<dim3(NROWS/64, DDIM/128, 3), 256, 0, stream>>>(Xh, Wt, bq, bk, bv, qb, kb, vt);
    attn_mfma<<<dim3(SS/64, HH, BB), 256, 0, stream>>>(qb, kb, vt, ob);
    proj_out<<<dim3(NROWS/64, DDIM/128), 256, 0, stream>>>(ob, Wt, bo, (float*)d_out);
}

// Round 4
// 133.996 us; speedup vs baseline: 1.6873x; 1.6873x over previous
//
#include <hip/hip_runtime.h>
#include <math.h>

#define BB 2
#define SS 2048
#define DDIM 768
#define HH 12
#define DH 64
#define NROWS (BB*SS)            // 4096
#define NTOK_D (NROWS*DDIM)      // 3145728

typedef _Float16 f16;
typedef _Float16 half4 __attribute__((ext_vector_type(4)));
typedef _Float16 half8 __attribute__((ext_vector_type(8)));
typedef float f32x4 __attribute__((ext_vector_type(4)));

#define MFMA16(a,b,c) __builtin_amdgcn_mfma_f32_16x16x32_f16((a),(b),(c),0,0,0)
#define QSCALE (0.125f * 1.44269504088896f)   // head-dim scale * log2(e)

// swizzled byte offset inside a 128B LDS row: 16B slot index ^= (row&7)
__device__ __forceinline__ int swz(int row, int chunk16) {
    return row*128 + ((chunk16 ^ (row & 7)) << 4);
}

// ---------------------------------------------------------------------------
// prep: x (f32) -> Xh (f16). 1536 blocks x 256 thr, 8 elems/thread.
// ---------------------------------------------------------------------------
__global__ __launch_bounds__(256) void prep_x(const float* __restrict__ x, f16* __restrict__ xh)
{
    int i = blockIdx.x * 256 + threadIdx.x;
    const float4* in = (const float4*)x;
    float4 a = in[i*2], b = in[i*2+1];
    half8 h = {(f16)a.x,(f16)a.y,(f16)a.z,(f16)a.w,(f16)b.x,(f16)b.y,(f16)b.z,(f16)b.w};
    *(half8*)(xh + (size_t)i*8) = h;
}

// ---------------------------------------------------------------------------
// prep: W[k][n] (f32) -> Wt[n][k] (f16), 4 matrices. grid (12,12,4), 256 thr.
// ---------------------------------------------------------------------------
__global__ __launch_bounds__(256) void prep_w(const float* __restrict__ Wq, const float* __restrict__ Wk,
                                              const float* __restrict__ Wv, const float* __restrict__ Wo,
                                              f16* __restrict__ Wt)
{
    const int z = blockIdx.z;
    const float* W = z==0 ? Wq : (z==1 ? Wk : (z==2 ? Wv : Wo));
    f16* out = Wt + (size_t)z * DDIM * DDIM;

    __shared__ float tile[64][65];
    const int t = threadIdx.x;
    const int k0 = blockIdx.x*64, n0 = blockIdx.y*64;

    const int kr = t >> 2, nc = (t & 3) * 16;
    #pragma unroll
    for (int i = 0; i < 4; ++i) {
        float4 v = *(const float4*)&W[(size_t)(k0+kr)*DDIM + n0 + nc + i*4];
        tile[kr][nc+i*4+0] = v.x; tile[kr][nc+i*4+1] = v.y;
        tile[kr][nc+i*4+2] = v.z; tile[kr][nc+i*4+3] = v.w;
    }
    __syncthreads();
    const int nr = t >> 2, kc = (t & 3) * 16;
    half8 h0, h1;
    #pragma unroll
    for (int j = 0; j < 8; ++j) {
        h0[j] = (f16)tile[kc + j][nr];
        h1[j] = (f16)tile[kc + 8 + j][nr];
    }
    *(half8*)&out[(size_t)(n0+nr)*DDIM + k0 + kc]     = h0;
    *(half8*)&out[(size_t)(n0+nr)*DDIM + k0 + kc + 8] = h1;
}

// ---------------------------------------------------------------------------
// QKV projection: C = Xh @ Wz + bias. q -> [B,H,S,Dh] pre-scaled by QSCALE,
// k -> [B,H,S,Dh], v -> TRANSPOSED [B,H,Dh,S].
// grid (4096/64, 768/128, 3), 256 thr (4 waves 2x2), BK=64, 16x16x32 MFMA.
// ---------------------------------------------------------------------------
__global__ __launch_bounds__(256) void proj_qkv(const f16* __restrict__ Xh, const f16* __restrict__ Wt,
        const float* __restrict__ bq, const float* __restrict__ bk, const float* __restrict__ bv,
        f16* __restrict__ qb, f16* __restrict__ kb2, f16* __restrict__ vtb)
{
    const int z = blockIdx.z;
    const f16* Wz = Wt + (size_t)z * DDIM * DDIM;
    const float* bias = z==0 ? bq : (z==1 ? bk : bv);
    const float qscale = (z==0) ? QSCALE : 1.0f;

    __shared__ __align__(16) unsigned char lds[24*1024];
    unsigned char* As = lds;            // 64 rows x 128B (m x k f16)
    unsigned char* Bs = lds + 8*1024;   // 128 rows x 128B (n x k f16)

    const int tid = threadIdx.x;
    const int l = tid & 63, w = tid >> 6;
    const int wm = w >> 1, wn = w & 1;
    const int m0 = blockIdx.x * 64, n0 = blockIdx.y * 128;

    f32x4 acc[2][4];
    #pragma unroll
    for (int i=0;i<2;i++)
        #pragma unroll
        for (int j=0;j<4;j++) { f32x4 zv = {0.f,0.f,0.f,0.f}; acc[i][j] = zv; }

    for (int k0 = 0; k0 < DDIM; k0 += 64) {
        __syncthreads();
        #pragma unroll
        for (int i = 0; i < 2; ++i) {
            int c = tid + i*256;
            int row = c >> 3, kc = c & 7;
            half8 v = *(const half8*)&Xh[(size_t)(m0+row)*DDIM + k0 + kc*8];
            *(half8*)(As + swz(row, kc)) = v;
        }
        #pragma unroll
        for (int i = 0; i < 4; ++i) {
            int c = tid + i*256;
            int row = c >> 3, kc = c & 7;
            half8 v = *(const half8*)&Wz[(size_t)(n0+row)*DDIM + k0 + kc*8];
            *(half8*)(Bs + swz(row, kc)) = v;
        }
        __syncthreads();

        half8 af[2][2], bf[4][2];
        #pragma unroll
        for (int mt = 0; mt < 2; ++mt) {
            int row = wm*32 + mt*16 + (l & 15);
            #pragma unroll
            for (int kh = 0; kh < 2; ++kh)
                af[mt][kh] = *(const half8*)(As + swz(row, kh*4 + (l>>4)));
        }
        #pragma unroll
        for (int nt = 0; nt < 4; ++nt) {
            int row = wn*64 + nt*16 + (l & 15);
            #pragma unroll
            for (int kh = 0; kh < 2; ++kh)
                bf[nt][kh] = *(const half8*)(Bs + swz(row, kh*4 + (l>>4)));
        }
        #pragma unroll
        for (int mt = 0; mt < 2; ++mt)
            #pragma unroll
            for (int nt = 0; nt < 4; ++nt) {
                acc[mt][nt] = MFMA16(af[mt][0], bf[nt][0], acc[mt][nt]);
                acc[mt][nt] = MFMA16(af[mt][1], bf[nt][1], acc[mt][nt]);
            }
    }

    if (z == 2) {
        // V transposed: [B,H,Dh,S]; r-quad is contiguous in s -> half4 store
        #pragma unroll
        for (int mt = 0; mt < 2; ++mt)
            #pragma unroll
            for (int nt = 0; nt < 4; ++nt) {
                int m = m0 + wm*32 + mt*16 + (l>>4)*4;   // s base (r=0)
                int n = n0 + wn*64 + nt*16 + (l & 15);
                int b = m >> 11, s = m & 2047;
                int h = n >> 6,  d = n & 63;
                float bs = bias[n];
                half4 o4 = {(f16)(acc[mt][nt][0] + bs), (f16)(acc[mt][nt][1] + bs),
                            (f16)(acc[mt][nt][2] + bs), (f16)(acc[mt][nt][3] + bs)};
                *(half4*)&vtb[(((size_t)(b*HH + h))*DH + d)*SS + s] = o4;
            }
    } else {
        f16* out = (z == 0) ? qb : kb2;
        #pragma unroll
        for (int mt = 0; mt < 2; ++mt)
            #pragma unroll
            for (int nt = 0; nt < 4; ++nt)
                #pragma unroll
                for (int r = 0; r < 4; ++r) {
                    int m = m0 + wm*32 + mt*16 + (l>>4)*4 + r;
                    int n = n0 + wn*64 + nt*16 + (l & 15);
                    float v = (acc[mt][nt][r] + bias[n]) * qscale;
                    int b = m >> 11, s = m & 2047;
                    int h = n >> 6,  d = n & 63;
                    out[(((size_t)(b*HH + h))*SS + s)*DH + d] = (f16)v;
                }
    }
}

// ---------------------------------------------------------------------------
// Flash attention: swapped-operand MFMA + cooperative LDS staging.
// grid (32, 12, 2), 128 thr = 2 waves x 32 q-rows. K and V^T tiles (8KB each)
// double-buffered in LDS, XOR-swizzled, staged with issue-early/write-late.
// QK^T: mfma(K, Q) -> S[key][q]; PV: mfma(V^T, P) -> O[d][q]. Softmax is
// lane-local (4 shfls per frag); P re-layout via per-wave 4KB LDS buffer.
// ---------------------------------------------------------------------------
__global__ __launch_bounds__(128) void attn_mfma(
        const f16* __restrict__ qbuf, const f16* __restrict__ kbuf,
        const f16* __restrict__ vtbuf, f16* __restrict__ obuf)
{
    // LDS: [K0 8K][V0 8K][K1 8K][V1 8K][Ps 2x4K] = 40KB
    __shared__ __align__(16) unsigned char lds[40*1024];

    const int tid = threadIdx.x;
    const int l = tid & 63, w = tid >> 6;      // w in 0..1
    const int g = l >> 4, qi = l & 15;
    const int q0 = blockIdx.x * 64 + w * 32;
    const size_t base = ((size_t)(blockIdx.z * HH + blockIdx.y)) * SS * DH;
    unsigned char* Pw = lds + 32*1024 + w*4096;

    // Q B-frags: lane n=q=q0+f*16+qi, k=d=kh*32+g*8+j (q pre-scaled)
    half8 qf[2][2];
    #pragma unroll
    for (int f = 0; f < 2; ++f)
        #pragma unroll
        for (int kh = 0; kh < 2; ++kh)
            qf[f][kh] = *(const half8*)&qbuf[base + (size_t)(q0 + f*16 + qi)*DH + kh*32 + g*8];

    f32x4 oacc[2][4];
    #pragma unroll
    for (int f = 0; f < 2; ++f)
        #pragma unroll
        for (int i = 0; i < 4; ++i) { f32x4 zv = {0.f,0.f,0.f,0.f}; oacc[f][i] = zv; }
    float mrun[2] = {-INFINITY, -INFINITY};
    float lsum[2] = {0.f, 0.f};

    // staging regs: 4 K chunks + 4 V chunks (16B each), 512 chunks/tile/buffer
    half8 sk[4], svv[4];

#define LOADT(t) { \
        _Pragma("unroll") \
        for (int i = 0; i < 4; ++i) { \
            int c = i*128 + tid, row = c >> 3, col = c & 7; \
            sk[i]  = *(const half8*)&kbuf[base + (size_t)((t)*64 + row)*DH + col*8]; \
            svv[i] = *(const half8*)&vtbuf[base + (size_t)row*SS + (t)*64 + col*8]; \
        } }

#define WRT(bufi) { \
        unsigned char* Kb_ = lds + (bufi)*16384; \
        unsigned char* Vb_ = Kb_ + 8192; \
        _Pragma("unroll") \
        for (int i = 0; i < 4; ++i) { \
            int c = i*128 + tid, row = c >> 3, col = c & 7; \
            *(half8*)(Kb_ + swz(row, col)) = sk[i]; \
            *(half8*)(Vb_ + swz(row, col)) = svv[i]; \
        } }

    LOADT(0); WRT(0);
    __syncthreads();

    for (int t = 0; t < 32; ++t) {
        const int cur = t & 1;
        if (t < 31) LOADT(t+1);          // issue-early (T14)

        unsigned char* Kb = lds + cur*16384;
        unsigned char* Vb = Kb + 8192;

        // K A-frags: lane m=key=mt*16+qi, k=d=kh*32+g*8+j
        half8 kf[8];
        #pragma unroll
        for (int mt = 0; mt < 4; ++mt)
            #pragma unroll
            for (int kh = 0; kh < 2; ++kh)
                kf[mt*2+kh] = *(const half8*)(Kb + swz(mt*16 + qi, kh*4 + g));

        // QK^T + online softmax + P-write, per q-frag
        #pragma unroll
        for (int f = 0; f < 2; ++f) {
            f32x4 sv[4];
            #pragma unroll
            for (int mt = 0; mt < 4; ++mt) {
                f32x4 zz = {0.f,0.f,0.f,0.f};
                zz = MFMA16(kf[mt*2+0], qf[f][0], zz);
                sv[mt] = MFMA16(kf[mt*2+1], qf[f][1], zz);
            }
            // lane owns q=q0+f*16+qi; keys = t*64 + mt*16 + g*4 + r
            float lm = -INFINITY;
            #pragma unroll
            for (int mt = 0; mt < 4; ++mt)
                #pragma unroll
                for (int r = 0; r < 4; ++r) lm = fmaxf(lm, sv[mt][r]);
            lm = fmaxf(lm, __shfl_xor(lm, 16));
            lm = fmaxf(lm, __shfl_xor(lm, 32));
            float mnew = fmaxf(mrun[f], lm);
            float fsc = exp2f(mrun[f] - mnew);
            mrun[f] = mnew;
            float rs = 0.f;
            #pragma unroll
            for (int mt = 0; mt < 4; ++mt)
                #pragma unroll
                for (int r = 0; r < 4; ++r) {
                    float pv = exp2f(sv[mt][r] - mnew);
                    sv[mt][r] = pv; rs += pv;
                }
            rs += __shfl_xor(rs, 16);
            rs += __shfl_xor(rs, 32);
            lsum[f] = lsum[f]*fsc + rs;
            #pragma unroll
            for (int dt = 0; dt < 4; ++dt)
                #pragma unroll
                for (int r = 0; r < 4; ++r) oacc[f][dt][r] *= fsc;
            // P -> per-wave LDS: row = f*16+qi, key byte = mt*32+g*8+r*2
            #pragma unroll
            for (int mt = 0; mt < 4; ++mt) {
                half4 pk = {(f16)sv[mt][0], (f16)sv[mt][1], (f16)sv[mt][2], (f16)sv[mt][3]};
                *(half4*)(Pw + swz(f*16 + qi, 2*mt + (g>>1)) + (g&1)*8) = pk;
            }
        }

        // V^T A-frags: lane m=d=dt*16+qi, k=key=kh*32+g*8+j
        half8 vf[8];
        #pragma unroll
        for (int dt = 0; dt < 4; ++dt)
            #pragma unroll
            for (int kh = 0; kh < 2; ++kh)
                vf[dt*2+kh] = *(const half8*)(Vb + swz(dt*16 + qi, kh*4 + g));

        #pragma unroll
        for (int f = 0; f < 2; ++f) {
            half8 pf0 = *(const half8*)(Pw + swz(f*16 + qi, g));
            half8 pf1 = *(const half8*)(Pw + swz(f*16 + qi, 4 + g));
            #pragma unroll
            for (int dt = 0; dt < 4; ++dt) {
                oacc[f][dt] = MFMA16(vf[dt*2+0], pf0, oacc[f][dt]);
                oacc[f][dt] = MFMA16(vf[dt*2+1], pf1, oacc[f][dt]);
            }
        }

        if (t < 31) WRT(cur^1);          // write-late into the other buffer
        __syncthreads();
    }

    // epilogue: O[d][q], lane col q = q0+f*16+qi, rows d = dt*16+g*4+r
    #pragma unroll
    for (int f = 0; f < 2; ++f) {
        const float inv = 1.0f / lsum[f];
        #pragma unroll
        for (int dt = 0; dt < 4; ++dt) {
            half4 o4 = {(f16)(oacc[f][dt][0]*inv), (f16)(oacc[f][dt][1]*inv),
                        (f16)(oacc[f][dt][2]*inv), (f16)(oacc[f][dt][3]*inv)};
            *(half4*)&obuf[base + (size_t)(q0 + f*16 + qi)*DH + dt*16 + g*4] = o4;
        }
    }
#undef LOADT
#undef WRT
}

// ---------------------------------------------------------------------------
// Output projection: C = obuf(gathered) @ Wo' + bo -> f32 out [4096][768].
// grid (64, 6), 256 thr.
// ---------------------------------------------------------------------------
__global__ __launch_bounds__(256) void proj_out(const f16* __restrict__ obuf, const f16* __restrict__ Wt,
                                                const float* __restrict__ bo, float* __restrict__ out)
{
    const f16* Wz = Wt + (size_t)3 * DDIM * DDIM;

    __shared__ __align__(16) unsigned char lds[24*1024];
    unsigned char* As = lds;
    unsigned char* Bs = lds + 8*1024;

    const int tid = threadIdx.x;
    const int l = tid & 63, w = tid >> 6;
    const int wm = w >> 1, wn = w & 1;
    const int m0 = blockIdx.x * 64, n0 = blockIdx.y * 128;

    f32x4 acc[2][4];
    #pragma unroll
    for (int i=0;i<2;i++)
        #pragma unroll
        for (int j=0;j<4;j++) { f32x4 zv = {0.f,0.f,0.f,0.f}; acc[i][j] = zv; }

    for (int k0 = 0; k0 < DDIM; k0 += 64) {
        const int h = k0 >> 6;
        __syncthreads();
        #pragma unroll
        for (int i = 0; i < 2; ++i) {
            int c = tid + i*256;
            int row = c >> 3, kc = c & 7;
            int m = m0 + row, b = m >> 11, s = m & 2047;
            half8 v = *(const half8*)&obuf[(((size_t)(b*HH + h))*SS + s)*DH + kc*8];
            *(half8*)(As + swz(row, kc)) = v;
        }
        #pragma unroll
        for (int i = 0; i < 4; ++i) {
            int c = tid + i*256;
            int row = c >> 3, kc = c & 7;
            half8 v = *(const half8*)&Wz[(size_t)(n0+row)*DDIM + k0 + kc*8];
            *(half8*)(Bs + swz(row, kc)) = v;
        }
        __syncthreads();

        half8 af[2][2], bf[4][2];
        #pragma unroll
        for (int mt = 0; mt < 2; ++mt) {
            int row = wm*32 + mt*16 + (l & 15);
            #pragma unroll
            for (int kh = 0; kh < 2; ++kh)
                af[mt][kh] = *(const half8*)(As + swz(row, kh*4 + (l>>4)));
        }
        #pragma unroll
        for (int nt = 0; nt < 4; ++nt) {
            int row = wn*64 + nt*16 + (l & 15);
            #pragma unroll
            for (int kh = 0; kh < 2; ++kh)
                bf[nt][kh] = *(const half8*)(Bs + swz(row, kh*4 + (l>>4)));
        }
        #pragma unroll
        for (int mt = 0; mt < 2; ++mt)
            #pragma unroll
            for (int nt = 0; nt < 4; ++nt) {
                acc[mt][nt] = MFMA16(af[mt][0], bf[nt][0], acc[mt][nt]);
                acc[mt][nt] = MFMA16(af[mt][1], bf[nt][1], acc[mt][nt]);
            }
    }

    #pragma unroll
    for (int mt = 0; mt < 2; ++mt)
        #pragma unroll
        for (int nt = 0; nt < 4; ++nt)
            #pragma unroll
            for (int r = 0; r < 4; ++r) {
                int m = m0 + wm*32 + mt*16 + (l>>4)*4 + r;
                int n = n0 + wn*64 + nt*16 + (l & 15);
                out[(size_t)m*DDIM + n] = acc[mt][nt][r] + bo[n];
            }
}

// ---------------------------------------------------------------------------
extern "C" void kernel_launch(void* const* d_in, const int* in_sizes, int n_in,
                              void* d_out, int out_size, void* d_ws, size_t ws_size,
                              hipStream_t stream)
{
    const float* x  = (const float*)d_in[0];
    const float* Wq = (const float*)d_in[1];
    const float* bq = (const float*)d_in[2];
    const float* Wk = (const float*)d_in[3];
    const float* bk = (const float*)d_in[4];
    const float* Wv = (const float*)d_in[5];
    const float* bv = (const float*)d_in[6];
    const float* Wo = (const float*)d_in[7];
    const float* bo = (const float*)d_in[8];

    char* ws = (char*)d_ws;
    const size_t XH_B  = (size_t)NTOK_D * 2;            // 6,291,456
    const size_t WT_B  = (size_t)4 * DDIM * DDIM * 2;   // 4,718,592
    const size_t HB_B  = (size_t)BB * HH * SS * DH * 2; // 6,291,456

    f16* Xh = (f16*)ws;
    f16* Wt = (f16*)(ws + XH_B);
    f16* qb = (f16*)(ws + XH_B + WT_B);
    f16* kb = (f16*)(ws + XH_B + WT_B + HB_B);
    f16* vt = (f16*)(ws + XH_B + WT_B + 2*HB_B);        // [B,H,Dh,S]
    f16* ob = (f16*)(ws + XH_B + WT_B + 3*HB_B);        // end ~36.2 MB

    prep_x<<<NTOK_D/(256*8), 256, 0, stream>>>(x, Xh);
    prep_w<<<dim3(DDIM/64, DDIM/64, 4), 256, 0, stream>>>(Wq, Wk, Wv, Wo, Wt);
    proj_qkv<<<dim3(NROWS/64, DDIM/128, 3), 256, 0, stream>>>(Xh, Wt, bq, bk, bv, qb, kb, vt);
    attn_mfma<<<dim3(SS/64, HH, BB), 128, 0, stream>>>(qb, kb, vt, ob);
    proj_out<<<dim3(NROWS/64, DDIM/128), 256, 0, stream>>>(ob, Wt, bo, (float*)d_out);
}